// Round 6
// baseline (106.571 us; speedup 1.0000x reference)
//
#include <hip/hip_runtime.h>
#include <hip/hip_bf16.h>

#define BN   8
#define NN   1024
#define CIN  256
#define COUT 256
#define HH   4
#define CC   64
#define ALPHA_C 0.2f

#define ROWS_K1 16

typedef __attribute__((ext_vector_type(8))) short short8;
typedef __attribute__((ext_vector_type(4))) float f32x4;

__device__ __forceinline__ unsigned short f2bf(float x) {
    __hip_bfloat16 h = __float2bfloat16(x);
    return *(unsigned short*)&h;
}

// ---------------- Kernel 1: h = X@W^T + b -> hbf_t[b][c][j] (bf16, transposed), l_src/l_dst
__global__ __launch_bounds__(256) void k1_gemm(
    const float* __restrict__ X, const float* __restrict__ W,
    const float* __restrict__ bias, const float* __restrict__ a,
    unsigned short* __restrict__ hbf_t, float* __restrict__ lsrc_t, float* __restrict__ ldst_t)
{
    __shared__ float4 Xs4[ROWS_K1 * 64];   // 16 rows x 256 f32 = 16 KB

    const int row0 = blockIdx.x * ROWS_K1;
    const int b    = row0 >> 10;
    const int j0   = row0 & 1023;          // within-batch row
    const float4* X4 = (const float4*)(X + (size_t)row0 * CIN);
    for (int v = threadIdx.x; v < ROWS_K1 * 64; v += 256) Xs4[v] = X4[v];
    __syncthreads();

    const int c = threadIdx.x;
    const float4* W4 = (const float4*)(W + (size_t)c * CIN);

    float acc[ROWS_K1];
    #pragma unroll
    for (int i = 0; i < ROWS_K1; ++i) acc[i] = 0.f;

    for (int k4 = 0; k4 < 64; ++k4) {
        float4 w4 = W4[k4];
        #pragma unroll
        for (int i = 0; i < ROWS_K1; ++i) {
            float4 x4 = Xs4[i * 64 + k4];
            acc[i] += x4.x * w4.x + x4.y * w4.y + x4.z * w4.z + x4.w * w4.w;
        }
    }

    const float bv = bias[c];
    const int hh = c >> 6, cc = c & 63;
    const float asrc = a[hh * (2 * CC) + cc];
    const float adst = a[hh * (2 * CC) + CC + cc];
    const int lane = threadIdx.x & 63;

    unsigned short us[ROWS_K1];
    #pragma unroll
    for (int i = 0; i < ROWS_K1; ++i) {
        float v = acc[i] + bv;
        us[i] = f2bf(v);
        float s1 = v * asrc, s2 = v * adst;
        #pragma unroll
        for (int off = 32; off >= 1; off >>= 1) {
            s1 += __shfl_xor(s1, off);
            s2 += __shfl_xor(s2, off);
        }
        if (lane == 0) {
            lsrc_t[((size_t)b * HH + hh) * NN + (j0 + i)] = s1;
            ldst_t[((size_t)b * HH + hh) * NN + (j0 + i)] = s2;
        }
    }
    // 16 bf16 = 32 B contiguous along j (j0 % 16 == 0 -> aligned)
    unsigned short* dst = hbf_t + ((size_t)(b * 256 + c) << 10) + j0;
    *(uint4*)(dst)     = *(uint4*)(us);
    *(uint4*)(dst + 8) = *(uint4*)(us + 8);
}

// ---------------- Kernel 2: masked softmax attention, PV via MFMA -------------------
// grid 512, 256 thr. b = bid&7 (one batch per XCD). wave = head. No LDS, no barriers.
// Lane l: A-row il = l&15, k-group jg = l>>4 (k = 8*jg+e). B-col = l&15.
// C/D: col = l&15, row = 4*jg + reg  (m89-verified layout).
// 2-slot software pipeline; __launch_bounds__(256,2) raises VGPR budget so the
// in-flight tile actually stays in registers (round-5 failure: 64-VGPR budget
// forced the compiler to sink prefetch loads next to uses).
struct Tile {
    int4   aA, aB;
    float4 dA, dB;
    short8 b0, b1, b2, b3;
};

__global__ __launch_bounds__(256, 2) void k2_attn(
    const unsigned short* __restrict__ hbf_t, const int* __restrict__ adj,
    const float* __restrict__ lsrc_t, const float* __restrict__ ldst_t,
    float* __restrict__ out)
{
    const int bid = blockIdx.x;
    const int b   = bid & 7;
    const int i0  = (bid >> 3) * 16;
    const int tid = threadIdx.x;
    const int h   = tid >> 6;
    const int l   = tid & 63;
    const int il  = l & 15;
    const int jg  = l >> 4;

    const float* ldst_b = ldst_t + ((size_t)b * HH + h) * NN;
    const float* lsrc_b = lsrc_t + ((size_t)b * HH + h) * NN + i0;

    // phase 0: mx = max_j ldst (valid softmax shift: lrelu is monotone)
    float mx = -3.4e38f;
    #pragma unroll
    for (int jt = 0; jt < 16; ++jt) mx = fmaxf(mx, ldst_b[jt * 64 + l]);
    #pragma unroll
    for (int off = 32; off >= 1; off >>= 1) mx = fmaxf(mx, __shfl_xor(mx, off));

    const float lsrc_v = lsrc_b[il];
    float t0 = lsrc_v + mx;
    const float m_r = (t0 > 0.f) ? t0 : ALPHA_C * t0;
    float lsum = 0.f;

    const int*   adj_r = adj + ((size_t)b * NN + i0 + il) * NN + jg * 8;
    const float* ld_r  = ldst_b + jg * 8;
    const short8* bp0 = (const short8*)(hbf_t + ((size_t)(b * 256 + h * 64 +  0 + il) << 10));
    const short8* bp1 = (const short8*)(hbf_t + ((size_t)(b * 256 + h * 64 + 16 + il) << 10));
    const short8* bp2 = (const short8*)(hbf_t + ((size_t)(b * 256 + h * 64 + 32 + il) << 10));
    const short8* bp3 = (const short8*)(hbf_t + ((size_t)(b * 256 + h * 64 + 48 + il) << 10));

    f32x4 acc0 = {0.f,0.f,0.f,0.f}, acc1 = acc0, acc2 = acc0, acc3 = acc0;

    #define LOAD_TILE(T, tt) {                                   \
        T.aA = *(const int4*)(adj_r + (tt) * 32);                \
        T.aB = *(const int4*)(adj_r + (tt) * 32 + 4);            \
        T.dA = *(const float4*)(ld_r + (tt) * 32);               \
        T.dB = *(const float4*)(ld_r + (tt) * 32 + 4);           \
        T.b0 = bp0[(tt) * 4 + jg]; T.b1 = bp1[(tt) * 4 + jg];    \
        T.b2 = bp2[(tt) * 4 + jg]; T.b3 = bp3[(tt) * 4 + jg]; }

    #define PELEM(AV, DV, IDX) {                                 \
        float s = lsrc_v + (DV);                                 \
        s = fmaxf(s, ALPHA_C * s);                               \
        float p = __expf(s - m_r);                               \
        p = (AV) ? p : 0.f;                                      \
        lsum += p;                                               \
        af[IDX] = (short)f2bf(p); }

    #define COMPUTE(T) {                                         \
        short8 af;                                               \
        PELEM(T.aA.x, T.dA.x, 0) PELEM(T.aA.y, T.dA.y, 1)        \
        PELEM(T.aA.z, T.dA.z, 2) PELEM(T.aA.w, T.dA.w, 3)        \
        PELEM(T.aB.x, T.dB.x, 4) PELEM(T.aB.y, T.dB.y, 5)        \
        PELEM(T.aB.z, T.dB.z, 6) PELEM(T.aB.w, T.dB.w, 7)        \
        acc0 = __builtin_amdgcn_mfma_f32_16x16x32_bf16(af, T.b0, acc0, 0, 0, 0); \
        acc1 = __builtin_amdgcn_mfma_f32_16x16x32_bf16(af, T.b1, acc1, 0, 0, 0); \
        acc2 = __builtin_amdgcn_mfma_f32_16x16x32_bf16(af, T.b2, acc2, 0, 0, 0); \
        acc3 = __builtin_amdgcn_mfma_f32_16x16x32_bf16(af, T.b3, acc3, 0, 0, 0); }

    Tile A, B;
    LOAD_TILE(A, 0)
    LOAD_TILE(B, 1)

    #pragma unroll
    for (int t = 0; t < 32; t += 2) {
        COMPUTE(A)
        if (t + 2 < 32) LOAD_TILE(A, t + 2)
        COMPUTE(B)
        if (t + 3 < 32) LOAD_TILE(B, t + 3)
    }

    #undef LOAD_TILE
    #undef PELEM
    #undef COMPUTE

    // ---- lsum: reduce across the 4 k-groups; lane x then holds lsum for il = x&15
    lsum += __shfl_xor(lsum, 16);
    lsum += __shfl_xor(lsum, 32);

    float inv[4];
    #pragma unroll
    for (int r = 0; r < 4; ++r) inv[r] = 1.0f / __shfl(lsum, 4 * jg + r);

    float* outp = out + ((size_t)b * NN + i0) * COUT + h * 64 + il;
    #pragma unroll
    for (int r = 0; r < 4; ++r) {
        const size_t ro = (size_t)(4 * jg + r) * COUT;
        outp[ro +  0] = acc0[r] * inv[r];
        outp[ro + 16] = acc1[r] * inv[r];
        outp[ro + 32] = acc2[r] * inv[r];
        outp[ro + 48] = acc3[r] * inv[r];
    }
}

extern "C" void kernel_launch(void* const* d_in, const int* in_sizes, int n_in,
                              void* d_out, int out_size, void* d_ws, size_t ws_size,
                              hipStream_t stream) {
    const float* X    = (const float*)d_in[0];
    const int*   adj  = (const int*)  d_in[1];
    const float* W    = (const float*)d_in[2];
    const float* bias = (const float*)d_in[3];
    const float* a    = (const float*)d_in[4];
    float* out = (float*)d_out;

    unsigned short* hbf_t = (unsigned short*)d_ws;                  // [b][c][j] bf16, 4 MB
    float* lsrc_t = (float*)(hbf_t + (size_t)BN * COUT * NN);       // [b][h][n] f32
    float* ldst_t = lsrc_t + (size_t)BN * HH * NN;

    k1_gemm<<<(BN * NN) / ROWS_K1, 256, 0, stream>>>(X, W, bias, a, hbf_t, lsrc_t, ldst_t);
    k2_attn<<<BN * (NN / 16), 256, 0, stream>>>(hbf_t, adj, lsrc_t, ldst_t, out);
}

// Round 7
// 91.948 us; speedup vs baseline: 1.1590x; 1.1590x over previous
//
#include <hip/hip_runtime.h>
#include <hip/hip_bf16.h>

#define BN   8
#define NN   1024
#define CIN  256
#define COUT 256
#define HH   4
#define CC   64
#define ALPHA_C 0.2f

#define ROWS_K1 16

typedef __attribute__((ext_vector_type(8))) short short8;
typedef __attribute__((ext_vector_type(4))) float f32x4;

__device__ __forceinline__ unsigned short f2bf(float x) {
    __hip_bfloat16 h = __float2bfloat16(x);
    return *(unsigned short*)&h;
}

// ---------------- Kernel 1: h = X@W^T + b -> hbf_t[b][c][j] (bf16, transposed), l_src/l_dst
__global__ __launch_bounds__(256) void k1_gemm(
    const float* __restrict__ X, const float* __restrict__ W,
    const float* __restrict__ bias, const float* __restrict__ a,
    unsigned short* __restrict__ hbf_t, float* __restrict__ lsrc_t, float* __restrict__ ldst_t)
{
    __shared__ float4 Xs4[ROWS_K1 * 64];   // 16 rows x 256 f32 = 16 KB

    const int row0 = blockIdx.x * ROWS_K1;
    const int b    = row0 >> 10;
    const int j0   = row0 & 1023;          // within-batch row
    const float4* X4 = (const float4*)(X + (size_t)row0 * CIN);
    for (int v = threadIdx.x; v < ROWS_K1 * 64; v += 256) Xs4[v] = X4[v];
    __syncthreads();

    const int c = threadIdx.x;
    const float4* W4 = (const float4*)(W + (size_t)c * CIN);

    float acc[ROWS_K1];
    #pragma unroll
    for (int i = 0; i < ROWS_K1; ++i) acc[i] = 0.f;

    for (int k4 = 0; k4 < 64; ++k4) {
        float4 w4 = W4[k4];
        #pragma unroll
        for (int i = 0; i < ROWS_K1; ++i) {
            float4 x4 = Xs4[i * 64 + k4];
            acc[i] += x4.x * w4.x + x4.y * w4.y + x4.z * w4.z + x4.w * w4.w;
        }
    }

    const float bv = bias[c];
    const int hh = c >> 6, cc = c & 63;
    const float asrc = a[hh * (2 * CC) + cc];
    const float adst = a[hh * (2 * CC) + CC + cc];
    const int lane = threadIdx.x & 63;

    unsigned short us[ROWS_K1];
    #pragma unroll
    for (int i = 0; i < ROWS_K1; ++i) {
        float v = acc[i] + bv;
        us[i] = f2bf(v);
        float s1 = v * asrc, s2 = v * adst;
        #pragma unroll
        for (int off = 32; off >= 1; off >>= 1) {
            s1 += __shfl_xor(s1, off);
            s2 += __shfl_xor(s2, off);
        }
        if (lane == 0) {
            lsrc_t[((size_t)b * HH + hh) * NN + (j0 + i)] = s1;
            ldst_t[((size_t)b * HH + hh) * NN + (j0 + i)] = s2;
        }
    }
    unsigned short* dst = hbf_t + ((size_t)(b * 256 + c) << 10) + j0;
    *(uint4*)(dst)     = *(uint4*)(us);
    *(uint4*)(dst + 8) = *(uint4*)(us + 8);
}

// ---------------- Kernel 2: masked softmax attention, PV via MFMA -------------------
// grid 512 x 1024thr (16 waves): wave wv = (jc,h) handles head h, j-chunk jc*256..+256.
// 2 blocks/CU -> 32 waves/CU (needs VGPR<=64 -> __launch_bounds__(1024,8)).
// Lane l: A-row il = l&15, k-group jg = l>>4. B-col = l&15. C/D: col=l&15, row=4*jg+r.
// Global softmax shift m (from max over ALL j) -> per-chunk partials add linearly;
// cross-chunk reduce + normalize in LDS at the end. No atomics, no extra kernel.
__global__ __launch_bounds__(1024, 8) void k2_attn(
    const unsigned short* __restrict__ hbf_t, const int* __restrict__ adj,
    const float* __restrict__ lsrc_t, const float* __restrict__ ldst_t,
    float* __restrict__ out)
{
    __shared__ float red[16][16][64];   // [wave][row][col-in-head]  64 KB
    __shared__ float lsumL[16][16];     // [wave][row]

    const int bid = blockIdx.x;
    const int b   = bid & 7;            // one batch per XCD
    const int i0  = (bid >> 3) * 16;
    const int tid = threadIdx.x;
    const int wv  = tid >> 6;           // 0..15
    const int h   = wv & 3;
    const int jc  = wv >> 2;            // j-chunk 0..3
    const int l   = tid & 63;
    const int il  = l & 15;
    const int jg  = l >> 4;

    const float* ldst_b = ldst_t + ((size_t)b * HH + h) * NN;
    const float* lsrc_b = lsrc_t + ((size_t)b * HH + h) * NN + i0;

    // phase 0: mx = max over ALL j of ldst (global shift, valid via lrelu monotonicity)
    float mx = -3.4e38f;
    #pragma unroll
    for (int jt = 0; jt < 16; ++jt) mx = fmaxf(mx, ldst_b[jt * 64 + l]);
    #pragma unroll
    for (int off = 32; off >= 1; off >>= 1) mx = fmaxf(mx, __shfl_xor(mx, off));

    const float lsrc_v = lsrc_b[il];
    float t0 = lsrc_v + mx;
    const float m_r = (t0 > 0.f) ? t0 : ALPHA_C * t0;
    float lsum = 0.f;

    const int*   adj_r = adj + ((size_t)b * NN + i0 + il) * NN + jc * 256 + jg * 8;
    const float* ld_r  = ldst_b + jc * 256 + jg * 8;
    const short8* bp0 = (const short8*)(hbf_t + (((size_t)(b * 256 + h * 64 +  0 + il)) << 10) + jc * 256);
    const short8* bp1 = (const short8*)(hbf_t + (((size_t)(b * 256 + h * 64 + 16 + il)) << 10) + jc * 256);
    const short8* bp2 = (const short8*)(hbf_t + (((size_t)(b * 256 + h * 64 + 32 + il)) << 10) + jc * 256);
    const short8* bp3 = (const short8*)(hbf_t + (((size_t)(b * 256 + h * 64 + 48 + il)) << 10) + jc * 256);

    f32x4 acc0 = {0.f,0.f,0.f,0.f}, acc1 = acc0, acc2 = acc0, acc3 = acc0;

    for (int t = 0; t < 8; ++t) {
        int4   aA = *(const int4*)(adj_r + t * 32);
        int4   aB = *(const int4*)(adj_r + t * 32 + 4);
        float4 dA = *(const float4*)(ld_r + t * 32);
        float4 dB = *(const float4*)(ld_r + t * 32 + 4);
        short8 b0 = bp0[t * 4 + jg], b1 = bp1[t * 4 + jg];
        short8 b2 = bp2[t * 4 + jg], b3 = bp3[t * 4 + jg];

        short8 af;
        #define PELEM(AV, DV, IDX) {                             \
            float s = lsrc_v + (DV);                             \
            s = fmaxf(s, ALPHA_C * s);                           \
            float p = __expf(s - m_r);                           \
            p = (AV) ? p : 0.f;                                  \
            lsum += p;                                           \
            af[IDX] = (short)f2bf(p); }
        PELEM(aA.x, dA.x, 0) PELEM(aA.y, dA.y, 1)
        PELEM(aA.z, dA.z, 2) PELEM(aA.w, dA.w, 3)
        PELEM(aB.x, dB.x, 4) PELEM(aB.y, dB.y, 5)
        PELEM(aB.z, dB.z, 6) PELEM(aB.w, dB.w, 7)
        #undef PELEM

        acc0 = __builtin_amdgcn_mfma_f32_16x16x32_bf16(af, b0, acc0, 0, 0, 0);
        acc1 = __builtin_amdgcn_mfma_f32_16x16x32_bf16(af, b1, acc1, 0, 0, 0);
        acc2 = __builtin_amdgcn_mfma_f32_16x16x32_bf16(af, b2, acc2, 0, 0, 0);
        acc3 = __builtin_amdgcn_mfma_f32_16x16x32_bf16(af, b3, acc3, 0, 0, 0);
    }

    // per-chunk lsum: reduce across the 4 k-groups -> lane x holds row x&15's sum
    lsum += __shfl_xor(lsum, 16);
    lsum += __shfl_xor(lsum, 32);
    if (l < 16) lsumL[wv][il] = lsum;

    // scatter this wave's partial C to LDS
    #pragma unroll
    for (int r = 0; r < 4; ++r) {
        const int row = 4 * jg + r;
        red[wv][row][ 0 + il] = acc0[r];
        red[wv][row][16 + il] = acc1[r];
        red[wv][row][32 + il] = acc2[r];
        red[wv][row][48 + il] = acc3[r];
    }
    __syncthreads();

    // waves 0..3: sum the 4 j-chunk partials for head wv, normalize, store
    if (wv < 4) {
        const int hh = wv;
        float* outp = out + ((size_t)b * NN + i0) * COUT + hh * 64 + l;
        #pragma unroll
        for (int i = 0; i < 16; ++i) {
            float s  = red[hh][i][l] + red[hh + 4][i][l]
                     + red[hh + 8][i][l] + red[hh + 12][i][l];
            float ls = lsumL[hh][i] + lsumL[hh + 4][i]
                     + lsumL[hh + 8][i] + lsumL[hh + 12][i];
            outp[(size_t)i * COUT] = s / ls;
        }
    }
}

extern "C" void kernel_launch(void* const* d_in, const int* in_sizes, int n_in,
                              void* d_out, int out_size, void* d_ws, size_t ws_size,
                              hipStream_t stream) {
    const float* X    = (const float*)d_in[0];
    const int*   adj  = (const int*)  d_in[1];
    const float* W    = (const float*)d_in[2];
    const float* bias = (const float*)d_in[3];
    const float* a    = (const float*)d_in[4];
    float* out = (float*)d_out;

    unsigned short* hbf_t = (unsigned short*)d_ws;                  // [b][c][j] bf16, 4 MB
    float* lsrc_t = (float*)(hbf_t + (size_t)BN * COUT * NN);       // [b][h][n] f32
    float* ldst_t = lsrc_t + (size_t)BN * HH * NN;

    k1_gemm<<<(BN * NN) / ROWS_K1, 256, 0, stream>>>(X, W, bias, a, hbf_t, lsrc_t, ldst_t);
    k2_attn<<<BN * (NN / 16), 1024, 0, stream>>>(hbf_t, adj, lsrc_t, ldst_t, out);
}

// Round 8
// 79.046 us; speedup vs baseline: 1.3482x; 1.1632x over previous
//
#include <hip/hip_runtime.h>
#include <hip/hip_bf16.h>

#define BN   8
#define NN   1024
#define CIN  256
#define COUT 256
#define HH   4
#define CC   64
#define ALPHA_C 0.2f

#define ROWS_K1 16

typedef __attribute__((ext_vector_type(8))) short short8;
typedef __attribute__((ext_vector_type(4))) float f32x4;

__device__ __forceinline__ unsigned short f2bf(float x) {
    __hip_bfloat16 h = __float2bfloat16(x);
    return *(unsigned short*)&h;
}

__device__ __forceinline__ void gl_lds16(const void* g, void* l) {
    __builtin_amdgcn_global_load_lds(
        (const __attribute__((address_space(1))) void*)g,
        (__attribute__((address_space(3))) void*)l, 16, 0, 0);
}

// h panel layout (bf16): panel tj covers j in [tj*32, tj*32+32).
// short index = ((b*32 + tj)*4 + sec)*2048... precisely: (((b*32+tj)*4 + sec)*256 + c)*8 + e
// where j = tj*32 + sec*8 + e. Panel (8192 shorts = 16 KB) is CONTIGUOUS.

// ---------------- Kernel 1: h = X@W^T + b -> panels, plus l_src/l_dst ----------------
__global__ __launch_bounds__(256) void k1_gemm(
    const float* __restrict__ X, const float* __restrict__ W,
    const float* __restrict__ bias, const float* __restrict__ a,
    unsigned short* __restrict__ hbf_p, float* __restrict__ lsrc_t, float* __restrict__ ldst_t)
{
    __shared__ float4 Xs4[ROWS_K1 * 64];   // 16 rows x 256 f32 = 16 KB

    const int row0 = blockIdx.x * ROWS_K1;
    const int b    = row0 >> 10;
    const int j0   = row0 & 1023;          // within-batch j of first row
    const float4* X4 = (const float4*)(X + (size_t)row0 * CIN);
    for (int v = threadIdx.x; v < ROWS_K1 * 64; v += 256) Xs4[v] = X4[v];
    __syncthreads();

    const int c = threadIdx.x;
    const float4* W4 = (const float4*)(W + (size_t)c * CIN);

    float acc[ROWS_K1];
    #pragma unroll
    for (int i = 0; i < ROWS_K1; ++i) acc[i] = 0.f;

    for (int k4 = 0; k4 < 64; ++k4) {
        float4 w4 = W4[k4];
        #pragma unroll
        for (int i = 0; i < ROWS_K1; ++i) {
            float4 x4 = Xs4[i * 64 + k4];
            acc[i] += x4.x * w4.x + x4.y * w4.y + x4.z * w4.z + x4.w * w4.w;
        }
    }

    const float bv = bias[c];
    const int hh = c >> 6, cc = c & 63;
    const float asrc = a[hh * (2 * CC) + cc];
    const float adst = a[hh * (2 * CC) + CC + cc];
    const int lane = threadIdx.x & 63;

    unsigned short us[ROWS_K1];
    #pragma unroll
    for (int i = 0; i < ROWS_K1; ++i) {
        float v = acc[i] + bv;
        us[i] = f2bf(v);
        float s1 = v * asrc, s2 = v * adst;
        #pragma unroll
        for (int off = 32; off >= 1; off >>= 1) {
            s1 += __shfl_xor(s1, off);
            s2 += __shfl_xor(s2, off);
        }
        if (lane == 0) {
            lsrc_t[((size_t)b * HH + hh) * NN + (j0 + i)] = s1;
            ldst_t[((size_t)b * HH + hh) * NN + (j0 + i)] = s2;
        }
    }
    // panel store: this block covers sections s0, s0+1 of panel (j0>>5)
    const int tj = j0 >> 5;
    const int s0 = (j0 & 31) >> 3;     // 0 or 2
    unsigned short* pan = hbf_p + (size_t)(b * 32 + tj) * 8192;
    *(uint4*)(pan + ((size_t)(s0 + 0) * 256 + c) * 8) = *(uint4*)(us);
    *(uint4*)(pan + ((size_t)(s0 + 1) * 256 + c) * 8) = *(uint4*)(us + 8);
}

// ---------------- Kernel 2: masked softmax attention, PV via MFMA -------------------
// grid 512 x 1024thr (16 waves). b = bid&7 (one batch per XCD). Wave (h=wv&3, jc=wv>>2).
// Round r: block stages panels 4r..4r+3 (64 KB linear) via global_load_lds; wave (h,jc)
// computes tile tj = 4r+jc. adj pre-packed to bits in LDS (ballot). No scattered VMEM
// in the hot loop: all per-lane fragment reads come from LDS.
// Lane l: il = l&15, jg = l>>4. A[m=il, k=8jg+e] = P. B[k, n=il] = h. D[4jg+r, il].
__global__ __launch_bounds__(1024, 4) void k2_attn(
    const unsigned short* __restrict__ hbf_p, const int* __restrict__ adj,
    const float* __restrict__ lsrc_t, const float* __restrict__ ldst_t,
    float* __restrict__ out)
{
    __shared__ __align__(16) unsigned char stage[65536];  // 64 KB staging / epilogue red
    __shared__ unsigned int adjw[32][16];                 // [j-word][i-row] bits
    __shared__ float lsumL[4][4][16];                     // [jc][h][il]

    const int bid = blockIdx.x;
    const int b   = bid & 7;
    const int i0  = (bid >> 3) * 16;
    const int tid = threadIdx.x;
    const int wv  = tid >> 6;          // 0..15
    const int h   = wv & 3;
    const int jc  = wv >> 2;
    const int l   = tid & 63;
    const int il  = l & 15;
    const int jg  = l >> 4;

    // ---- pack adj: wave wv packs row i0+wv (coalesced reads + ballot) ----
    {
        const int* arow = adj + ((size_t)b * NN + i0 + wv) * NN;
        #pragma unroll 4
        for (int it = 0; it < 16; ++it) {
            int av = arow[it * 64 + l];
            unsigned long long m = __ballot(av != 0);
            if (l == 0) {
                adjw[2 * it    ][wv] = (unsigned int)m;
                adjw[2 * it + 1][wv] = (unsigned int)(m >> 32);
            }
        }
    }

    // ---- mx = max over all j of ldst[h] (valid softmax shift: lrelu monotone) ----
    const float* ldst_h = ldst_t + ((size_t)b * HH + h) * NN;
    float mx = -3.4e38f;
    #pragma unroll
    for (int jt = 0; jt < 16; ++jt) mx = fmaxf(mx, ldst_h[jt * 64 + l]);
    #pragma unroll
    for (int off = 32; off >= 1; off >>= 1) mx = fmaxf(mx, __shfl_xor(mx, off));

    const float lsrc_v = lsrc_t[((size_t)b * HH + h) * NN + i0 + il];
    const float t0  = lsrc_v + mx;
    const float m_r = fmaxf(t0, ALPHA_C * t0);
    float lsum = 0.f;

    // constant LDS byte offsets for the 4 B-fragments (single-buffered stage)
    const int bo0 = jc * 16384 + jg * 4096 + (h * 64 +  0 + il) * 16;
    const int bo1 = jc * 16384 + jg * 4096 + (h * 64 + 16 + il) * 16;
    const int bo2 = jc * 16384 + jg * 4096 + (h * 64 + 32 + il) * 16;
    const int bo3 = jc * 16384 + jg * 4096 + (h * 64 + 48 + il) * 16;

    f32x4 acc0 = {0.f,0.f,0.f,0.f}, acc1 = acc0, acc2 = acc0, acc3 = acc0;

    const unsigned short* gpan = hbf_p + (size_t)(b * 32) * 8192;

    __syncthreads();   // adjw ready

    for (int r = 0; r < 8; ++r) {
        // ---- issue staging of panels 4r..4r+3 (64 KB linear, coalesced) ----
        const unsigned short* gsrc = gpan + (size_t)(4 * r) * 8192;
        #pragma unroll
        for (int k = 0; k < 4; ++k) {
            const int chunk = k * 16 + wv;
            gl_lds16(gsrc + chunk * 512 + l * 8, (char*)stage + chunk * 1024);
        }

        // ---- P-compute (register/broadcast-only) overlaps the staging ----
        const int tj = 4 * r + jc;
        const unsigned int bw = adjw[tj][il] >> (jg * 8);
        float4 dA = *(const float4*)(ldst_h + tj * 32 + jg * 8);
        float4 dB = *(const float4*)(ldst_h + tj * 32 + jg * 8 + 4);
        short8 af;
        #define PELEM(DV, E) {                                   \
            float s = lsrc_v + (DV);                             \
            s = fmaxf(s, ALPHA_C * s);                           \
            float p = __expf(s - m_r);                           \
            p = (bw & (1u << (E))) ? p : 0.f;                    \
            lsum += p;                                           \
            af[E] = (short)f2bf(p); }
        PELEM(dA.x, 0) PELEM(dA.y, 1) PELEM(dA.z, 2) PELEM(dA.w, 3)
        PELEM(dB.x, 4) PELEM(dB.y, 5) PELEM(dB.z, 6) PELEM(dB.w, 7)
        #undef PELEM

        __syncthreads();   // staging complete (drains vmcnt)

        short8 b0 = *(const short8*)(stage + bo0);
        short8 b1 = *(const short8*)(stage + bo1);
        short8 b2 = *(const short8*)(stage + bo2);
        short8 b3 = *(const short8*)(stage + bo3);

        acc0 = __builtin_amdgcn_mfma_f32_16x16x32_bf16(af, b0, acc0, 0, 0, 0);
        acc1 = __builtin_amdgcn_mfma_f32_16x16x32_bf16(af, b1, acc1, 0, 0, 0);
        acc2 = __builtin_amdgcn_mfma_f32_16x16x32_bf16(af, b2, acc2, 0, 0, 0);
        acc3 = __builtin_amdgcn_mfma_f32_16x16x32_bf16(af, b3, acc3, 0, 0, 0);

        __syncthreads();   // all reads of stage done before next round's writes
    }

    // ---- lsum reduce over jg; partials to LDS ----
    lsum += __shfl_xor(lsum, 16);
    lsum += __shfl_xor(lsum, 32);
    if (l < 16) lsumL[jc][h][il] = lsum;

    // ---- partial C to LDS (reuse stage as red[jc][h][16i][64c]) ----
    float* red = (float*)stage;
    {
        const int base = ((jc * 4 + h) * 16 + 4 * jg) * 64 + il;
        #pragma unroll
        for (int rr = 0; rr < 4; ++rr) {
            red[base + rr * 64 +  0] = acc0[rr];
            red[base + rr * 64 + 16] = acc1[rr];
            red[base + rr * 64 + 32] = acc2[rr];
            red[base + rr * 64 + 48] = acc3[rr];
        }
    }
    __syncthreads();

    // ---- final: sum 4 jc-partials, normalize, store ----
    {
        const int i  = tid >> 6;       // 0..15
        const int cq = tid & 63;       // 0..63
        #pragma unroll
        for (int hh = 0; hh < 4; ++hh) {
            float v  = red[((0 * 4 + hh) * 16 + i) * 64 + cq]
                     + red[((1 * 4 + hh) * 16 + i) * 64 + cq]
                     + red[((2 * 4 + hh) * 16 + i) * 64 + cq]
                     + red[((3 * 4 + hh) * 16 + i) * 64 + cq];
            float ls = lsumL[0][hh][i] + lsumL[1][hh][i]
                     + lsumL[2][hh][i] + lsumL[3][hh][i];
            out[((size_t)b * NN + i0 + i) * COUT + hh * 64 + cq] = v / ls;
        }
    }
}

extern "C" void kernel_launch(void* const* d_in, const int* in_sizes, int n_in,
                              void* d_out, int out_size, void* d_ws, size_t ws_size,
                              hipStream_t stream) {
    const float* X    = (const float*)d_in[0];
    const int*   adj  = (const int*)  d_in[1];
    const float* W    = (const float*)d_in[2];
    const float* bias = (const float*)d_in[3];
    const float* a    = (const float*)d_in[4];
    float* out = (float*)d_out;

    unsigned short* hbf_p = (unsigned short*)d_ws;                  // panels, 4 MB
    float* lsrc_t = (float*)(hbf_p + (size_t)BN * 32 * 8192);       // [b][h][n] f32
    float* ldst_t = lsrc_t + (size_t)BN * HH * NN;

    k1_gemm<<<(BN * NN) / ROWS_K1, 256, 0, stream>>>(X, W, bias, a, hbf_p, lsrc_t, ldst_t);
    k2_attn<<<BN * (NN / 16), 1024, 0, stream>>>(hbf_p, adj, lsrc_t, ldst_t, out);
}

// Round 9
// 53.297 us; speedup vs baseline: 1.9996x; 1.4831x over previous
//
#include <hip/hip_runtime.h>
#include <hip/hip_bf16.h>

#define BN   8
#define NN   1024
#define CIN  256
#define COUT 256
#define HH   4
#define CC   64
#define ALPHA_C 0.2f

typedef __attribute__((ext_vector_type(8))) short short8;
typedef __attribute__((ext_vector_type(4))) float f32x4;

__device__ __forceinline__ unsigned short f2bf(float x) {
    __hip_bfloat16 h = __float2bfloat16(x);
    return *(unsigned short*)&h;
}
__device__ __forceinline__ float bf2f(unsigned short u) {
    return __uint_as_float(((unsigned int)u) << 16);
}
__device__ __forceinline__ void gl_lds16(const void* g, void* l) {
    __builtin_amdgcn_global_load_lds(
        (const __attribute__((address_space(1))) void*)g,
        (__attribute__((address_space(3))) void*)l, 16, 0, 0);
}

// ---------------- Kernel 0: pack W (fp32) -> Wh/Wl bf16 panels -----------------------
// Panel layout: element (k, n) at ((kc*4+jg)*256 + n)*8 + e, where k = kc*32+jg*8+e.
// B-frag for lane (il,jg): 16 B contiguous; 16 il-lanes -> 256 B contiguous (coalesced).
__global__ __launch_bounds__(256) void k0_wpack(
    const float* __restrict__ W, unsigned short* __restrict__ Whp, unsigned short* __restrict__ Wlp)
{
    const int bid = blockIdx.x;          // kc*4 + jg
    const int n = threadIdx.x;
    const int fi = n * 64 + (bid >> 2) * 8 + (bid & 3) * 2;
    const float4* W4 = (const float4*)W;
    float4 wa = W4[fi], wb = W4[fi + 1];
    float xs[8] = {wa.x, wa.y, wa.z, wa.w, wb.x, wb.y, wb.z, wb.w};
    unsigned short hh[8], ll[8];
    #pragma unroll
    for (int e = 0; e < 8; ++e) {
        hh[e] = f2bf(xs[e]);
        ll[e] = f2bf(xs[e] - bf2f(hh[e]));
    }
    *(uint4*)(Whp + ((size_t)bid * 256 + n) * 8) = *(uint4*)hh;
    *(uint4*)(Wlp + ((size_t)bid * 256 + n) * 8) = *(uint4*)ll;
}

// ---------------- Kernel 1: h = X@W^T + b via bf16x3 MFMA ---------------------------
// grid 256 x 1024thr (16 waves). Block = 32 rows (one h-panel). wave wv: mq=wv>>3 (M-half),
// no=wv&7 (32-col slice). Lane l: il=l&15, jg=l>>4.
// A row=il k=8jg+e (from swizzled LDS); B col=il same k (coalesced from W panels);
// D row=4jg+r col=il. Epilogue: bias, lsrc/ldst (fp32), h -> bf16 panel store.
__global__ __launch_bounds__(1024, 4) void k1_gemm(
    const float* __restrict__ X, const float* __restrict__ bias, const float* __restrict__ a,
    const unsigned short* __restrict__ Whp, const unsigned short* __restrict__ Wlp,
    unsigned short* __restrict__ hbf_p, float* __restrict__ lsrc_t, float* __restrict__ ldst_t)
{
    __shared__ __align__(16) unsigned short Xh[32 * 256];   // 16 KB, XOR-swizzled
    __shared__ __align__(16) unsigned short Xl[32 * 256];   // 16 KB
    __shared__ float lsP[2][8][2][16];                      // [src/dst][no][mq][m16]

    const int bid = blockIdx.x;
    const int row0 = bid * 32;
    const int b  = bid >> 5;
    const int tj = bid & 31;
    const int tid = threadIdx.x;
    const int wv = tid >> 6, l = tid & 63, il = l & 15, jg = l >> 4;
    const int mq = wv >> 3, no = wv & 7;

    // ---- stage X rows -> bf16 hi/lo LDS (swizzle: byte-in-row ^ ((row&7)<<4)) ----
    {
        const float4* X4 = (const float4*)(X + (size_t)row0 * CIN);
        #pragma unroll
        for (int it = 0; it < 2; ++it) {
            int f = it * 1024 + tid;            // 0..2047 (32 rows x 64 float4)
            int r = f >> 6, k4 = f & 63;
            float4 x = X4[f];
            unsigned short h0 = f2bf(x.x), h1 = f2bf(x.y), h2 = f2bf(x.z), h3 = f2bf(x.w);
            unsigned short l0 = f2bf(x.x - bf2f(h0)), l1 = f2bf(x.y - bf2f(h1));
            unsigned short l2 = f2bf(x.z - bf2f(h2)), l3 = f2bf(x.w - bf2f(h3));
            unsigned short hs[4] = {h0, h1, h2, h3}, ls[4] = {l0, l1, l2, l3};
            int off = r * 512 + ((k4 * 8) ^ ((r & 7) << 4));
            *(uint2*)((char*)Xh + off) = *(uint2*)hs;
            *(uint2*)((char*)Xl + off) = *(uint2*)ls;
        }
    }
    __syncthreads();

    // ---- MFMA K-loop ----
    f32x4 acc0 = {0.f, 0.f, 0.f, 0.f}, acc1 = acc0;
    {
        const int abase = (mq * 16 + il) * 512;
        const int swz = (il & 7) << 4;
        const short8* Wh8 = (const short8*)Whp;
        const short8* Wl8 = (const short8*)Wlp;
        const int nb = no * 32 + il;
        #pragma unroll
        for (int kc = 0; kc < 8; ++kc) {
            const int ab = abase + ((kc * 64 + jg * 16) ^ swz);
            short8 Ah = *(const short8*)((const char*)Xh + ab);
            short8 Al = *(const short8*)((const char*)Xl + ab);
            const int pidx = (kc * 4 + jg) * 256 + nb;
            short8 Bh0 = Wh8[pidx],      Bl0 = Wl8[pidx];
            short8 Bh1 = Wh8[pidx + 16], Bl1 = Wl8[pidx + 16];
            acc0 = __builtin_amdgcn_mfma_f32_16x16x32_bf16(Ah, Bh0, acc0, 0, 0, 0);
            acc1 = __builtin_amdgcn_mfma_f32_16x16x32_bf16(Ah, Bh1, acc1, 0, 0, 0);
            acc0 = __builtin_amdgcn_mfma_f32_16x16x32_bf16(Ah, Bl0, acc0, 0, 0, 0);
            acc1 = __builtin_amdgcn_mfma_f32_16x16x32_bf16(Ah, Bl1, acc1, 0, 0, 0);
            acc0 = __builtin_amdgcn_mfma_f32_16x16x32_bf16(Al, Bh0, acc0, 0, 0, 0);
            acc1 = __builtin_amdgcn_mfma_f32_16x16x32_bf16(Al, Bh1, acc1, 0, 0, 0);
        }
    }

    // ---- epilogue: bias, logits, reductions ----
    const int c0 = no * 32 + il, c1 = c0 + 16;
    const float bia0 = bias[c0], bia1 = bias[c1];
    const int hh = no >> 1;
    const int cc0 = c0 & 63, cc1 = c1 & 63;
    const float as0 = a[hh * 128 + cc0],      as1 = a[hh * 128 + cc1];
    const float ad0 = a[hh * 128 + 64 + cc0], ad1 = a[hh * 128 + 64 + cc1];

    float v0[4], v1[4], psrc[4], pdst[4];
    #pragma unroll
    for (int r = 0; r < 4; ++r) {
        v0[r] = acc0[r] + bia0;
        v1[r] = acc1[r] + bia1;
        psrc[r] = v0[r] * as0 + v1[r] * as1;
        pdst[r] = v0[r] * ad0 + v1[r] * ad1;
    }
    #pragma unroll
    for (int off = 8; off >= 1; off >>= 1) {
        #pragma unroll
        for (int r = 0; r < 4; ++r) {
            psrc[r] += __shfl_xor(psrc[r], off);
            pdst[r] += __shfl_xor(pdst[r], off);
        }
    }
    __syncthreads();   // all waves done reading Xh/Xl

    // h -> bf16 into hp (reuse Xh), panel layout [sec][c][e]
    unsigned short* hp = Xh;
    #pragma unroll
    for (int r = 0; r < 4; ++r) {
        int m = mq * 16 + 4 * jg + r;
        int sec = m >> 3, e = m & 7;
        hp[(sec * 256 + c0) * 8 + e] = f2bf(v0[r]);
        hp[(sec * 256 + c1) * 8 + e] = f2bf(v1[r]);
    }
    if (il == 0) {
        #pragma unroll
        for (int r = 0; r < 4; ++r) {
            lsP[0][no][mq][4 * jg + r] = psrc[r];
            lsP[1][no][mq][4 * jg + r] = pdst[r];
        }
    }
    __syncthreads();

    // copy panel out (16 KB coalesced)
    {
        uint4* dst4 = (uint4*)(hbf_p + (size_t)(b * 32 + tj) * 8192);
        dst4[tid] = ((const uint4*)hp)[tid];
    }
    // lsrc/ldst out (head h spans no = 2h, 2h+1)
    if (tid < 256) {
        int sd = tid >> 7, rem = tid & 127, h2 = rem >> 5, m = rem & 31;
        float v = lsP[sd][2 * h2][m >> 4][m & 15] + lsP[sd][2 * h2 + 1][m >> 4][m & 15];
        float* dst = sd ? ldst_t : lsrc_t;
        dst[((size_t)b * HH + h2) * NN + tj * 32 + m] = v;
    }
}

// ---------------- Kernel 2: masked softmax attention, PV via MFMA -------------------
// grid 256 x 1024thr (16 waves). b = bid&7 (one batch per XCD), i0 = (bid>>3)*32.
// wave wv: h = wv&3, mq = (wv>>2)&1, jh = wv>>3. Round r covers j = 64r..64r+63
// (2 panels); wave computes panel jh. Prefetch-next double-buffered staging:
// STAGE(r+1) issued BEFORE compute(r); one __syncthreads per round drains it after
// the compute phase covered its latency (T3 minimum 2-phase recipe).
__global__ __launch_bounds__(1024, 4) void k2_attn(
    const unsigned short* __restrict__ hbf_p, const int* __restrict__ adj,
    const float* __restrict__ lsrc_t, const float* __restrict__ ldst_t,
    float* __restrict__ out)
{
    __shared__ __align__(16) char stage[2][32768];   // 64 KB h-tile dbuf; epilogue: red
    __shared__ unsigned int adjw[32][32];            // [j-word][i-row]
    __shared__ float ldsTbl[4 * 1024];               // ldst per head, 16 KB
    __shared__ float lsumS[2][4][32];                // [jh][h][m]

    const int bid = blockIdx.x;
    const int b  = bid & 7;
    const int i0 = (bid >> 3) * 32;
    const int tid = threadIdx.x;
    const int wv = tid >> 6, l = tid & 63, il = l & 15, jg = l >> 4;
    const int h = wv & 3, mq = (wv >> 2) & 1, jh = wv >> 3;

    // ---- prologue: adj bit-pack (2 rows/wave), ldst table, stage round 0 ----
    {
        const int* arow = adj + ((size_t)b * NN + i0 + 2 * wv) * NN;
        #pragma unroll
        for (int rr = 0; rr < 2; ++rr)
            for (int it = 0; it < 16; ++it) {
                int av = arow[rr * NN + it * 64 + l];
                unsigned long long mb = __ballot(av != 0);
                if (l == 0) {
                    adjw[2 * it][2 * wv + rr] = (unsigned int)mb;
                    adjw[2 * it + 1][2 * wv + rr] = (unsigned int)(mb >> 32);
                }
            }
    }
    ((float4*)ldsTbl)[tid] = ((const float4*)(ldst_t + (size_t)b * HH * NN))[tid];

    const unsigned short* gpan = hbf_p + (size_t)b * 32 * 8192;
    gl_lds16(gpan + (size_t)(wv * 64 + l) * 8, stage[0] + wv * 1024 + l * 16);
    gl_lds16(gpan + (size_t)(1024 + wv * 64 + l) * 8, stage[0] + 16384 + wv * 1024 + l * 16);

    const float lsrc_v = lsrc_t[((size_t)b * HH + h) * NN + i0 + mq * 16 + il];

    __syncthreads();   // adjw + ldsTbl + stage0 ready

    // ---- mx = max over all j of ldst[h] (valid softmax shift: lrelu monotone) ----
    float mx = -3.4e38f;
    #pragma unroll
    for (int jt = 0; jt < 16; ++jt) mx = fmaxf(mx, ldsTbl[h * 1024 + jt * 64 + l]);
    #pragma unroll
    for (int off = 32; off >= 1; off >>= 1) mx = fmaxf(mx, __shfl_xor(mx, off));
    const float t0 = lsrc_v + mx;
    const float m_r = fmaxf(t0, ALPHA_C * t0);
    float lsum = 0.f;

    f32x4 acc0 = {0.f,0.f,0.f,0.f}, acc1 = acc0, acc2 = acc0, acc3 = acc0;

    int cur = 0;
    for (int r = 0; r < 16; ++r) {
        // ---- prefetch round r+1 into the other buffer ----
        if (r < 15) {
            const unsigned short* gs = gpan + (size_t)(2 * (r + 1)) * 8192;
            char* db = stage[cur ^ 1];
            gl_lds16(gs + (size_t)(wv * 64 + l) * 8, db + wv * 1024 + l * 16);
            gl_lds16(gs + (size_t)(1024 + wv * 64 + l) * 8, db + 16384 + wv * 1024 + l * 16);
        }
        // ---- P for this wave's panel (registers + LDS broadcasts only) ----
        unsigned int bw = adjw[2 * r + jh][mq * 16 + il] >> (jg * 8);
        const float* lt = ldsTbl + h * 1024 + r * 64 + jh * 32 + jg * 8;
        float4 dA = *(const float4*)lt;
        float4 dB = *(const float4*)(lt + 4);
        short8 af;
        #define PELEM(DV, E) {                                   \
            float s = lsrc_v + (DV);                             \
            s = fmaxf(s, ALPHA_C * s);                           \
            float p = __expf(s - m_r);                           \
            p = (bw & (1u << (E))) ? p : 0.f;                    \
            lsum += p;                                           \
            af[E] = (short)f2bf(p); }
        PELEM(dA.x, 0) PELEM(dA.y, 1) PELEM(dA.z, 2) PELEM(dA.w, 3)
        PELEM(dB.x, 4) PELEM(dB.y, 5) PELEM(dB.z, 6) PELEM(dB.w, 7)
        #undef PELEM

        // ---- B-frags from current buffer + 4 MFMAs ----
        const char* pb = stage[cur] + jh * 16384;
        const int off = jg * 4096 + (h * 64 + il) * 16;
        short8 b0 = *(const short8*)(pb + off);
        short8 b1 = *(const short8*)(pb + off + 256);
        short8 b2 = *(const short8*)(pb + off + 512);
        short8 b3 = *(const short8*)(pb + off + 768);
        acc0 = __builtin_amdgcn_mfma_f32_16x16x32_bf16(af, b0, acc0, 0, 0, 0);
        acc1 = __builtin_amdgcn_mfma_f32_16x16x32_bf16(af, b1, acc1, 0, 0, 0);
        acc2 = __builtin_amdgcn_mfma_f32_16x16x32_bf16(af, b2, acc2, 0, 0, 0);
        acc3 = __builtin_amdgcn_mfma_f32_16x16x32_bf16(af, b3, acc3, 0, 0, 0);

        __syncthreads();   // drains prefetch (overlapped with compute above)
        cur ^= 1;
    }

    // ---- lsum reduce over jg, stash per (jh,h,m) ----
    lsum += __shfl_xor(lsum, 16);
    lsum += __shfl_xor(lsum, 32);
    if (l < 16) lsumS[jh][h][mq * 16 + l] = lsum;

    // ---- partial C to LDS (reuse stage: red[wv][16 rows][64 cols]) ----
    float* red = (float*)stage;
    {
        float* rw = red + wv * 1024;
        #pragma unroll
        for (int rr = 0; rr < 4; ++rr) {
            rw[(4 * jg + rr) * 64 +  0 + il] = acc0[rr];
            rw[(4 * jg + rr) * 64 + 16 + il] = acc1[rr];
            rw[(4 * jg + rr) * 64 + 32 + il] = acc2[rr];
            rw[(4 * jg + rr) * 64 + 48 + il] = acc3[rr];
        }
    }
    __syncthreads();

    // ---- final: sum jh pair, normalize, coalesced store ----
    #pragma unroll
    for (int e = 0; e < 8; ++e) {
        int flat = e * 1024 + tid;
        int m = flat >> 8, c = flat & 255;
        int h2 = c >> 6, mq2 = m >> 4, r16 = m & 15, cl = c & 63;
        float vA = red[(mq2 * 4 + h2) * 1024 + r16 * 64 + cl];
        float vB = red[(8 + mq2 * 4 + h2) * 1024 + r16 * 64 + cl];
        float ls = lsumS[0][h2][m] + lsumS[1][h2][m];
        out[((size_t)b * NN + i0 + m) * 256 + c] = (vA + vB) / ls;
    }
}

extern "C" void kernel_launch(void* const* d_in, const int* in_sizes, int n_in,
                              void* d_out, int out_size, void* d_ws, size_t ws_size,
                              hipStream_t stream) {
    const float* X    = (const float*)d_in[0];
    const int*   adj  = (const int*)  d_in[1];
    const float* W    = (const float*)d_in[2];
    const float* bias = (const float*)d_in[3];
    const float* a    = (const float*)d_in[4];
    float* out = (float*)d_out;

    unsigned short* hbf_p = (unsigned short*)d_ws;                  // 8*32 panels, 4 MB
    float* lsrc_t = (float*)(hbf_p + (size_t)BN * 32 * 8192);       // [b][h][n]
    float* ldst_t = lsrc_t + (size_t)BN * HH * NN;
    unsigned short* Whp = (unsigned short*)(ldst_t + (size_t)BN * HH * NN);  // 128 KB
    unsigned short* Wlp = Whp + 65536;                                        // 128 KB

    k0_wpack<<<32, 256, 0, stream>>>(W, Whp, Wlp);
    k1_gemm<<<256, 1024, 0, stream>>>(X, bias, a, Whp, Wlp, hbf_p, lsrc_t, ldst_t);
    k2_attn<<<256, 1024, 0, stream>>>(hbf_p, adj, lsrc_t, ldst_t, out);
}

// Round 10
// 48.132 us; speedup vs baseline: 2.2142x; 1.1073x over previous
//
#include <hip/hip_runtime.h>
#include <hip/hip_bf16.h>

#define BN   8
#define NN   1024
#define CIN  256
#define COUT 256
#define HH   4
#define CC   64
#define ALPHA_C 0.2f

typedef __attribute__((ext_vector_type(8))) short short8;
typedef __attribute__((ext_vector_type(4))) float f32x4;

__device__ __forceinline__ unsigned short f2bf(float x) {
    __hip_bfloat16 h = __float2bfloat16(x);
    return *(unsigned short*)&h;
}
__device__ __forceinline__ float bf2f(unsigned short u) {
    return __uint_as_float(((unsigned int)u) << 16);
}

// ---------------- Kernel 0: pack W (fp32) -> Wh/Wl bf16 panels -----------------------
__global__ __launch_bounds__(256) void k0_wpack(
    const float* __restrict__ W, unsigned short* __restrict__ Whp, unsigned short* __restrict__ Wlp)
{
    const int bid = blockIdx.x;          // kc*4 + jg
    const int n = threadIdx.x;
    const int fi = n * 64 + (bid >> 2) * 8 + (bid & 3) * 2;
    const float4* W4 = (const float4*)W;
    float4 wa = W4[fi], wb = W4[fi + 1];
    float xs[8] = {wa.x, wa.y, wa.z, wa.w, wb.x, wb.y, wb.z, wb.w};
    unsigned short hh[8], ll[8];
    #pragma unroll
    for (int e = 0; e < 8; ++e) {
        hh[e] = f2bf(xs[e]);
        ll[e] = f2bf(xs[e] - bf2f(hh[e]));
    }
    *(uint4*)(Whp + ((size_t)bid * 256 + n) * 8) = *(uint4*)hh;
    *(uint4*)(Wlp + ((size_t)bid * 256 + n) * 8) = *(uint4*)ll;
}

// ---------------- Kernel 1: h = X@W^T + b via bf16x3 MFMA ---------------------------
// grid 256 x 1024thr. Block = 32 rows -> one h-panel. Panel layout (NEW, k2-coalesced):
// element (j', c) at ((c>>6)*256 + ((c&63)>>4)*64 + (j'>>3)*16 + (c&15))*8 + (j'&7)
// so a k2 wave's B-frag load (h, sub) is lane-contiguous 1 KB.
__global__ __launch_bounds__(1024, 4) void k1_gemm(
    const float* __restrict__ X, const float* __restrict__ bias, const float* __restrict__ a,
    const unsigned short* __restrict__ Whp, const unsigned short* __restrict__ Wlp,
    unsigned short* __restrict__ hbf_p, float* __restrict__ lsrc_t, float* __restrict__ ldst_t)
{
    __shared__ __align__(16) unsigned short Xh[32 * 256];   // 16 KB, XOR-swizzled
    __shared__ __align__(16) unsigned short Xl[32 * 256];   // 16 KB
    __shared__ float lsP[2][8][2][16];                      // [src/dst][no][mq][m16]

    const int bid = blockIdx.x;
    const int row0 = bid * 32;
    const int b  = bid >> 5;
    const int tj = bid & 31;
    const int tid = threadIdx.x;
    const int wv = tid >> 6, l = tid & 63, il = l & 15, jg = l >> 4;
    const int mq = wv >> 3, no = wv & 7;

    // ---- stage X rows -> bf16 hi/lo LDS (swizzle: byte-in-row ^ ((row&7)<<4)) ----
    {
        const float4* X4 = (const float4*)(X + (size_t)row0 * CIN);
        #pragma unroll
        for (int it = 0; it < 2; ++it) {
            int f = it * 1024 + tid;            // 0..2047 (32 rows x 64 float4)
            int r = f >> 6, k4 = f & 63;
            float4 x = X4[f];
            unsigned short h0 = f2bf(x.x), h1 = f2bf(x.y), h2 = f2bf(x.z), h3 = f2bf(x.w);
            unsigned short l0 = f2bf(x.x - bf2f(h0)), l1 = f2bf(x.y - bf2f(h1));
            unsigned short l2 = f2bf(x.z - bf2f(h2)), l3 = f2bf(x.w - bf2f(h3));
            unsigned short hs[4] = {h0, h1, h2, h3}, ls[4] = {l0, l1, l2, l3};
            int off = r * 512 + ((k4 * 8) ^ ((r & 7) << 4));
            *(uint2*)((char*)Xh + off) = *(uint2*)hs;
            *(uint2*)((char*)Xl + off) = *(uint2*)ls;
        }
    }
    __syncthreads();

    // ---- MFMA K-loop ----
    f32x4 acc0 = {0.f, 0.f, 0.f, 0.f}, acc1 = acc0;
    {
        const int abase = (mq * 16 + il) * 512;
        const int swz = (il & 7) << 4;
        const short8* Wh8 = (const short8*)Whp;
        const short8* Wl8 = (const short8*)Wlp;
        const int nb = no * 32 + il;
        #pragma unroll
        for (int kc = 0; kc < 8; ++kc) {
            const int ab = abase + ((kc * 64 + jg * 16) ^ swz);
            short8 Ah = *(const short8*)((const char*)Xh + ab);
            short8 Al = *(const short8*)((const char*)Xl + ab);
            const int pidx = (kc * 4 + jg) * 256 + nb;
            short8 Bh0 = Wh8[pidx],      Bl0 = Wl8[pidx];
            short8 Bh1 = Wh8[pidx + 16], Bl1 = Wl8[pidx + 16];
            acc0 = __builtin_amdgcn_mfma_f32_16x16x32_bf16(Ah, Bh0, acc0, 0, 0, 0);
            acc1 = __builtin_amdgcn_mfma_f32_16x16x32_bf16(Ah, Bh1, acc1, 0, 0, 0);
            acc0 = __builtin_amdgcn_mfma_f32_16x16x32_bf16(Ah, Bl0, acc0, 0, 0, 0);
            acc1 = __builtin_amdgcn_mfma_f32_16x16x32_bf16(Ah, Bl1, acc1, 0, 0, 0);
            acc0 = __builtin_amdgcn_mfma_f32_16x16x32_bf16(Al, Bh0, acc0, 0, 0, 0);
            acc1 = __builtin_amdgcn_mfma_f32_16x16x32_bf16(Al, Bh1, acc1, 0, 0, 0);
        }
    }

    // ---- epilogue: bias, logits, reductions ----
    const int c0 = no * 32 + il, c1 = c0 + 16;
    const float bia0 = bias[c0], bia1 = bias[c1];
    const int hh = no >> 1;
    const int cc0 = c0 & 63, cc1 = c1 & 63;
    const float as0 = a[hh * 128 + cc0],      as1 = a[hh * 128 + cc1];
    const float ad0 = a[hh * 128 + 64 + cc0], ad1 = a[hh * 128 + 64 + cc1];

    float v0[4], v1[4], psrc[4], pdst[4];
    #pragma unroll
    for (int r = 0; r < 4; ++r) {
        v0[r] = acc0[r] + bia0;
        v1[r] = acc1[r] + bia1;
        psrc[r] = v0[r] * as0 + v1[r] * as1;
        pdst[r] = v0[r] * ad0 + v1[r] * ad1;
    }
    #pragma unroll
    for (int off = 8; off >= 1; off >>= 1) {
        #pragma unroll
        for (int r = 0; r < 4; ++r) {
            psrc[r] += __shfl_xor(psrc[r], off);
            pdst[r] += __shfl_xor(pdst[r], off);
        }
    }
    __syncthreads();   // all waves done reading Xh/Xl

    // h -> bf16 into hp (reuse Xh), NEW panel layout
    unsigned short* hp = Xh;
    #pragma unroll
    for (int r = 0; r < 4; ++r) {
        int m = mq * 16 + 4 * jg + r;
        int base = (m >> 3) * 128 + (m & 7);
        hp[(c0 >> 6) * 2048 + ((c0 & 63) >> 4) * 512 + base + (c0 & 15) * 8] = f2bf(v0[r]);
        hp[(c1 >> 6) * 2048 + ((c1 & 63) >> 4) * 512 + base + (c1 & 15) * 8] = f2bf(v1[r]);
    }
    if (il == 0) {
        #pragma unroll
        for (int r = 0; r < 4; ++r) {
            lsP[0][no][mq][4 * jg + r] = psrc[r];
            lsP[1][no][mq][4 * jg + r] = pdst[r];
        }
    }
    __syncthreads();

    // copy panel out (16 KB coalesced)
    {
        uint4* dst4 = (uint4*)(hbf_p + (size_t)(b * 32 + tj) * 8192);
        dst4[tid] = ((const uint4*)hp)[tid];
    }
    // lsrc/ldst out
    if (tid < 256) {
        int sd = tid >> 7, rem = tid & 127, h2 = rem >> 5, m = rem & 31;
        float v = lsP[sd][2 * h2][m >> 4][m & 15] + lsP[sd][2 * h2 + 1][m >> 4][m & 15];
        float* dst = sd ? ldst_t : lsrc_t;
        dst[((size_t)b * HH + h2) * NN + tj * 32 + m] = v;
    }
}

// ---------------- Kernel 2: masked softmax attention, PV via MFMA -------------------
// grid 256 x 1024thr (16 waves). b = bid&7, i0 = (bid>>3)*32. wave wv: h=wv&3,
// mq=(wv>>2)&1, jh=wv>>3. NO h staging (panels are L2-resident: Common-mistake #7),
// NO in-loop barriers. B-frags are direct per-lane loads, lane-contiguous 1 KB/wave,
// 1-round register prefetch; latency hidden by PELEM VALU + free-running waves.
__global__ __launch_bounds__(1024, 4) void k2_attn(
    const unsigned short* __restrict__ hbf_p, const int* __restrict__ adj,
    const float* __restrict__ lsrc_t, const float* __restrict__ ldst_t,
    float* __restrict__ out)
{
    __shared__ __align__(16) char smem[65536];   // [adjw 4KB | ldsTbl 16KB] -> epilogue red 64KB
    __shared__ float lsumS[2][4][32];            // [jh][h][m]

    unsigned int (*adjw)[32] = (unsigned int (*)[32])smem;   // [j-word][i-row]
    float* ldsTbl = (float*)(smem + 4096);                   // ldst, 4 heads x 1024

    const int bid = blockIdx.x;
    const int b  = bid & 7;
    const int i0 = (bid >> 3) * 32;
    const int tid = threadIdx.x;
    const int wv = tid >> 6, l = tid & 63, il = l & 15, jg = l >> 4;
    const int h = wv & 3, mq = (wv >> 2) & 1, jh = wv >> 3;

    // ---- prologue: adj bit-pack (2 rows/wave) + ldst table ----
    {
        const int* arow = adj + ((size_t)b * NN + i0 + 2 * wv) * NN;
        #pragma unroll
        for (int rr = 0; rr < 2; ++rr)
            #pragma unroll 4
            for (int it = 0; it < 16; ++it) {
                int av = arow[rr * NN + it * 64 + l];
                unsigned long long mb = __ballot(av != 0);
                if (l == 0) {
                    adjw[2 * it][2 * wv + rr] = (unsigned int)mb;
                    adjw[2 * it + 1][2 * wv + rr] = (unsigned int)(mb >> 32);
                }
            }
    }
    ((float4*)ldsTbl)[tid] = ((const float4*)(ldst_t + (size_t)b * HH * NN))[tid];

    const float lsrc_v = lsrc_t[((size_t)b * HH + h) * NN + i0 + mq * 16 + il];

    __syncthreads();   // adjw + ldsTbl ready

    // ---- mx = max over all j of ldst[h] (valid softmax shift: lrelu monotone) ----
    float mx = -3.4e38f;
    #pragma unroll
    for (int jt = 0; jt < 16; ++jt) mx = fmaxf(mx, ldsTbl[h * 1024 + jt * 64 + l]);
    #pragma unroll
    for (int off = 32; off >= 1; off >>= 1) mx = fmaxf(mx, __shfl_xor(mx, off));
    const float t0 = lsrc_v + mx;
    const float m_r = fmaxf(t0, ALPHA_C * t0);
    float lsum = 0.f;

    f32x4 acc0 = {0.f,0.f,0.f,0.f}, acc1 = acc0, acc2 = acc0, acc3 = acc0;

    // B-frag pointers: frag (tj, h, s) for lane l at short8 index tj*1024 + h*256 + s*64 + l
    const short8* bfp = (const short8*)(hbf_p + (size_t)b * 32 * 8192);
    const int fb = h * 256 + l;

    int tj = jh;                    // round 0 panel for this wave
    short8 c0 = bfp[tj * 1024 + fb +   0];
    short8 c1 = bfp[tj * 1024 + fb +  64];
    short8 c2 = bfp[tj * 1024 + fb + 128];
    short8 c3 = bfp[tj * 1024 + fb + 192];

    for (int r = 0; r < 16; ++r) {
        // ---- prefetch next round's 4 B-frags (uses: next iteration) ----
        const int tjn = (r < 15) ? (2 * (r + 1) + jh) : tj;
        short8 n0 = bfp[tjn * 1024 + fb +   0];
        short8 n1 = bfp[tjn * 1024 + fb +  64];
        short8 n2 = bfp[tjn * 1024 + fb + 128];
        short8 n3 = bfp[tjn * 1024 + fb + 192];

        // ---- P for this wave's panel (registers + LDS broadcasts only) ----
        unsigned int bw = adjw[2 * r + jh][mq * 16 + il] >> (jg * 8);
        const float* lt = ldsTbl + h * 1024 + r * 64 + jh * 32 + jg * 8;
        float4 dA = *(const float4*)lt;
        float4 dB = *(const float4*)(lt + 4);
        short8 af;
        #define PELEM(DV, E) {                                   \
            float s = lsrc_v + (DV);                             \
            s = fmaxf(s, ALPHA_C * s);                           \
            float p = __expf(s - m_r);                           \
            p = (bw & (1u << (E))) ? p : 0.f;                    \
            lsum += p;                                           \
            af[E] = (short)f2bf(p); }
        PELEM(dA.x, 0) PELEM(dA.y, 1) PELEM(dA.z, 2) PELEM(dA.w, 3)
        PELEM(dB.x, 4) PELEM(dB.y, 5) PELEM(dB.z, 6) PELEM(dB.w, 7)
        #undef PELEM

        acc0 = __builtin_amdgcn_mfma_f32_16x16x32_bf16(af, c0, acc0, 0, 0, 0);
        acc1 = __builtin_amdgcn_mfma_f32_16x16x32_bf16(af, c1, acc1, 0, 0, 0);
        acc2 = __builtin_amdgcn_mfma_f32_16x16x32_bf16(af, c2, acc2, 0, 0, 0);
        acc3 = __builtin_amdgcn_mfma_f32_16x16x32_bf16(af, c3, acc3, 0, 0, 0);

        c0 = n0; c1 = n1; c2 = n2; c3 = n3;
        tj = tjn;
    }

    // ---- lsum reduce over jg ----
    lsum += __shfl_xor(lsum, 16);
    lsum += __shfl_xor(lsum, 32);
    if (l < 16) lsumS[jh][h][mq * 16 + l] = lsum;
    __syncthreads();   // all adjw/ldsTbl reads done; red may overlay

    // ---- partial C to LDS: red[wv][16 rows][64 cols] ----
    float* red = (float*)smem;
    {
        float* rw = red + wv * 1024;
        #pragma unroll
        for (int rr = 0; rr < 4; ++rr) {
            rw[(4 * jg + rr) * 64 +  0 + il] = acc0[rr];
            rw[(4 * jg + rr) * 64 + 16 + il] = acc1[rr];
            rw[(4 * jg + rr) * 64 + 32 + il] = acc2[rr];
            rw[(4 * jg + rr) * 64 + 48 + il] = acc3[rr];
        }
    }
    __syncthreads();

    // ---- final: sum jh pair, normalize, coalesced store ----
    #pragma unroll
    for (int e = 0; e < 8; ++e) {
        int flat = e * 1024 + tid;
        int m = flat >> 8, c = flat & 255;
        int h2 = c >> 6, mq2 = m >> 4, r16 = m & 15, cl = c & 63;
        float vA = red[(mq2 * 4 + h2) * 1024 + r16 * 64 + cl];
        float vB = red[(8 + mq2 * 4 + h2) * 1024 + r16 * 64 + cl];
        float ls = lsumS[0][h2][m] + lsumS[1][h2][m];
        out[((size_t)b * NN + i0 + m) * 256 + c] = (vA + vB) / ls;
    }
}

extern "C" void kernel_launch(void* const* d_in, const int* in_sizes, int n_in,
                              void* d_out, int out_size, void* d_ws, size_t ws_size,
                              hipStream_t stream) {
    const float* X    = (const float*)d_in[0];
    const int*   adj  = (const int*)  d_in[1];
    const float* W    = (const float*)d_in[2];
    const float* bias = (const float*)d_in[3];
    const float* a    = (const float*)d_in[4];
    float* out = (float*)d_out;

    unsigned short* hbf_p = (unsigned short*)d_ws;                  // 8*32 panels, 4 MB
    float* lsrc_t = (float*)(hbf_p + (size_t)BN * 32 * 8192);       // [b][h][n]
    float* ldst_t = lsrc_t + (size_t)BN * HH * NN;
    unsigned short* Whp = (unsigned short*)(ldst_t + (size_t)BN * HH * NN);  // 128 KB
    unsigned short* Wlp = Whp + 65536;                                        // 128 KB

    k0_wpack<<<32, 256, 0, stream>>>(W, Whp, Wlp);
    k1_gemm<<<256, 1024, 0, stream>>>(X, bias, a, Whp, Wlp, hbf_p, lsrc_t, ldst_t);
    k2_attn<<<256, 1024, 0, stream>>>(hbf_p, adj, lsrc_t, ldst_t, out);
}